// Round 1
// baseline (131.349 us; speedup 1.0000x reference)
//
#include <hip/hip_runtime.h>

#define T_LEN  1048576
#define NROWS  32
#define NTAPS  128
#define N2     32
#define BLOCK  256
#define R_OUT  16
#define OPB    (BLOCK * R_OUT)      /* 4096 outputs per block */
#define TILE   (OPB + NTAPS)        /* 4224 floats staged */
#define TILE4  (TILE / 4)           /* 1056 float4 */

// XOR swizzle at float4 granularity: spreads the 64-B-strided per-thread
// windows evenly across the 8 16-B bank groups.
__device__ __forceinline__ int swz4(int q) { return q ^ ((q >> 3) & 7); }

// ---- kernel 1: SSM impulse response h[0..127] (+D at 0), stored reversed+plain ----
__global__ __launch_bounds__(NTAPS) void ssm_taps(
    const float* __restrict__ w_real, const float* __restrict__ w_imag,
    const float* __restrict__ log_dt,
    const float* __restrict__ C_real, const float* __restrict__ C_imag,
    const float* __restrict__ B_real, const float* __restrict__ B_imag,
    const float* __restrict__ Dp, float* __restrict__ ws) {
  const int k = threadIdx.x;                 // 0..127
  const float dt = expf(log_dt[0]);
  const float kf = (float)k;
  float acc = 0.f;
  for (int n = 0; n < N2; ++n) {
    const float a  = dt * w_real[n];         // matches dtA = dt*w op order
    const float b  = dt * w_imag[n];
    const float cr = C_real[n], ci = C_imag[n];
    const float br = B_real[n], bi = B_imag[n];
    const float coef_r = cr * br - ci * bi;  // C*B complex
    const float coef_i = cr * bi + ci * br;
    const float e = expf(a * kf);
    float s, c;
    sincosf(b * kf, &s, &c);                 // exp(i*b*k)
    acc += e * (coef_r * c - coef_i * s);    // Re(coef * e^{dtA k})
  }
  if (k == 0) acc += Dp[0];
  ws[127 - k]  = acc;                        // g[j] = h[127-j]  (main conv)
  ws[NTAPS + k] = acc;                       // h[k]             (wraparound fixup)
}

// ---- kernel 2: main FIR conv.  y[n] = sum_j g[j] * x[n-254+j], zero-padded left ----
__global__ __launch_bounds__(BLOCK) void ssm_conv(
    const float* __restrict__ x, const float* __restrict__ ws,
    float* __restrict__ out) {
  __shared__ __align__(16) float tile[TILE];
  __shared__ __align__(16) float gk[NTAPS];

  const int row = blockIdx.y;
  const int n0  = blockIdx.x * OPB;
  const float* __restrict__ xrow = x + (size_t)row * T_LEN;
  const int tid = threadIdx.x;

  if (tid < NTAPS) gk[tid] = ws[tid];
  // stage x[n0-254 .. n0-254+TILE-1] (zeros for negative index), swizzled
  for (int i = tid; i < TILE; i += BLOCK) {
    const int gi = n0 - 254 + i;
    const float v = (gi >= 0) ? xrow[gi] : 0.f;
    tile[(swz4(i >> 2) << 2) | (i & 3)] = v;
  }
  __syncthreads();

  const float4* __restrict__ tile4 = (const float4*)tile;
  const int base4 = tid * (R_OUT / 4);       // thread window starts at float 16*tid

  float acc[R_OUT];
#pragma unroll
  for (int r = 0; r < R_OUT; ++r) acc[r] = 0.f;

  // rotating 24-float register window; xw[(l + 8*jb) % 24] = tile[base + 8*jb + l]
  float xw[24];
#pragma unroll
  for (int i = 0; i < 6; ++i) {
    const float4 v = tile4[swz4(base4 + i)];
    xw[4 * i + 0] = v.x; xw[4 * i + 1] = v.y;
    xw[4 * i + 2] = v.z; xw[4 * i + 3] = v.w;
  }

#pragma unroll
  for (int jb = 0; jb < NTAPS / 8; ++jb) {   // 16 tap-blocks of 8
    float gv[8];
    *(float4*)&gv[0] = *(const float4*)&gk[jb * 8];
    *(float4*)&gv[4] = *(const float4*)&gk[jb * 8 + 4];
#pragma unroll
    for (int js = 0; js < 8; ++js) {
#pragma unroll
      for (int r = 0; r < R_OUT; ++r) {
        acc[r] = fmaf(gv[js], xw[(js + r + 8 * jb) % 24], acc[r]);
      }
    }
    if (jb < NTAPS / 8 - 1) {                // refill oldest 8 slots
#pragma unroll
      for (int i = 0; i < 2; ++i) {
        const float4 v = tile4[swz4(base4 + 2 * jb + 6 + i)];
        xw[(8 * jb + 4 * i + 0) % 24] = v.x;
        xw[(8 * jb + 4 * i + 1) % 24] = v.y;
        xw[(8 * jb + 4 * i + 2) % 24] = v.z;
        xw[(8 * jb + 4 * i + 3) % 24] = v.w;
      }
    }
  }

  float* __restrict__ orow = out + (size_t)row * T_LEN + n0 + tid * R_OUT;
#pragma unroll
  for (int i = 0; i < 4; ++i) {
    float4 v;
    v.x = acc[4 * i + 0]; v.y = acc[4 * i + 1];
    v.z = acc[4 * i + 2]; v.w = acc[4 * i + 3];
    *(float4*)(orow + 4 * i) = v;
  }
}

// ---- kernel 3: wraparound fixup for n in [0,126]:  y[n] = sum_{k=n+1}^{127} h[k] x[T+n-k] ----
__global__ __launch_bounds__(NTAPS) void ssm_fix(
    const float* __restrict__ x, const float* __restrict__ ws,
    float* __restrict__ out) {
  const int row = blockIdx.x;
  const int n = threadIdx.x;
  if (n >= NTAPS - 1) return;
  const float* __restrict__ h = ws + NTAPS;
  const float* __restrict__ xrow = x + (size_t)row * T_LEN;
  float acc = 0.f;
  for (int k = n + 1; k < NTAPS; ++k)
    acc += h[k] * xrow[T_LEN + n - k];
  out[(size_t)row * T_LEN + n] = acc;
}

extern "C" void kernel_launch(void* const* d_in, const int* in_sizes, int n_in,
                              void* d_out, int out_size, void* d_ws, size_t ws_size,
                              hipStream_t stream) {
  const float* x      = (const float*)d_in[0];
  const float* w_real = (const float*)d_in[1];
  const float* w_imag = (const float*)d_in[2];
  const float* log_dt = (const float*)d_in[3];
  const float* C_real = (const float*)d_in[4];
  const float* C_imag = (const float*)d_in[5];
  const float* B_real = (const float*)d_in[6];
  const float* B_imag = (const float*)d_in[7];
  const float* Dp     = (const float*)d_in[8];
  float* out = (float*)d_out;
  float* ws  = (float*)d_ws;

  ssm_taps<<<1, NTAPS, 0, stream>>>(w_real, w_imag, log_dt,
                                    C_real, C_imag, B_real, B_imag, Dp, ws);
  dim3 grid(T_LEN / OPB, NROWS);
  ssm_conv<<<grid, BLOCK, 0, stream>>>(x, ws, out);
  ssm_fix<<<NROWS, NTAPS, 0, stream>>>(x, ws, out);
}

// Round 2
// 105.700 us; speedup vs baseline: 1.2427x; 1.2427x over previous
//
#include <hip/hip_runtime.h>

#define T_LEN  1048576
#define NROWS  32
#define NTAPS  128
#define N2     32
#define BLOCK  256
#define WAVES  4
#define TPW    2              /* 32x32 tiles per wave */
#define NOUT   8192           /* outputs per block = 4 waves * 2 tiles * 1024 */
#define NCH    10             /* K chunks of 16: covers k in [0,160) band */
#define STG    8320           /* staged bf16 elems per array (halo 254 + 8192 - 126) */
#define SMEM_BYTES 33792      /* max(2*2*STG, 8*1056*4) */

typedef __attribute__((ext_vector_type(8)))  short  short8;
typedef __attribute__((ext_vector_type(16))) float  f32x16;

__device__ __forceinline__ unsigned short f2bf(float f) {
  unsigned u = __builtin_bit_cast(unsigned, f);
  u += 0x7FFFu + ((u >> 16) & 1u);            // RNE (finite inputs only)
  return (unsigned short)(u >> 16);
}
__device__ __forceinline__ float bf2f(unsigned short h) {
  unsigned u = ((unsigned)h) << 16;
  return __builtin_bit_cast(float, u);
}

// ---- kernel 1: impulse response h[0..127] (+D at 0) and per-lane bf16 hi/lo
// Toeplitz A-fragments: A_c[m,s] = h[m + 127 - 16c - s], m=lane&31, s=8*(lane>>5)+i
__global__ __launch_bounds__(NTAPS) void ssm_taps(
    const float* __restrict__ w_real, const float* __restrict__ w_imag,
    const float* __restrict__ log_dt,
    const float* __restrict__ C_real, const float* __restrict__ C_imag,
    const float* __restrict__ B_real, const float* __restrict__ B_imag,
    const float* __restrict__ Dp, float* __restrict__ ws) {
  __shared__ float hsh[NTAPS];
  const int k = threadIdx.x;                 // 0..127
  const float dt = expf(log_dt[0]);
  const float kf = (float)k;
  float acc = 0.f;
  for (int n = 0; n < N2; ++n) {
    const float a  = dt * w_real[n];
    const float b  = dt * w_imag[n];
    const float cr = C_real[n], ci = C_imag[n];
    const float br = B_real[n], bi = B_imag[n];
    const float coef_r = cr * br - ci * bi;
    const float coef_i = cr * bi + ci * br;
    const float e = expf(a * kf);
    float s, c;
    sincosf(b * kf, &s, &c);
    acc += e * (coef_r * c - coef_i * s);
  }
  if (k == 0) acc += Dp[0];
  ws[k]  = acc;                              // plain h (fix kernel)
  hsh[k] = acc;
  __syncthreads();
  if (k < 64) {
    const int m = k & 31, g = k >> 5;
    unsigned short* AH = (unsigned short*)(ws + NTAPS);
    unsigned short* AL = AH + NCH * 64 * 8;
    for (int c = 0; c < NCH; ++c)
      for (int i = 0; i < 8; ++i) {
        const int idx = m + 127 - 16 * c - 8 * g - i;
        const float v = (idx >= 0 && idx < NTAPS) ? hsh[idx] : 0.f;
        const unsigned short hi = f2bf(v);
        const unsigned short lo = f2bf(v - bf2f(hi));
        AH[(c * 64 + k) * 8 + i] = hi;
        AL[(c * 64 + k) * 8 + i] = lo;
      }
  }
}

// ---- kernel 2: implicit-GEMM FIR via mfma_f32_32x32x16_bf16, hi/lo split ----
__global__ __launch_bounds__(BLOCK, 3) void ssm_conv(
    const float* __restrict__ x, const float* __restrict__ ws,
    float* __restrict__ out) {
  __shared__ __align__(16) unsigned char smem[SMEM_BYTES];
  unsigned short* xh = (unsigned short*)smem;          // STG bf16 hi
  unsigned short* xl = xh + STG;                        // STG bf16 lo

  const int tid  = threadIdx.x;
  const int lane = tid & 63;
  const int wid  = tid >> 6;
  const int row  = blockIdx.y;
  const int n0   = blockIdx.x * NOUT;
  const float* __restrict__ xrow = x + (size_t)row * T_LEN;

  // A fragments (same for every block; coalesced dwordx4, L2-cached)
  short8 AHf[NCH], ALf[NCH];
  const short8* wsA = (const short8*)(ws + NTAPS);
  #pragma unroll
  for (int c = 0; c < NCH; ++c) {
    AHf[c] = wsA[c * 64 + lane];
    ALf[c] = wsA[NCH * 64 + c * 64 + lane];
  }

  // stage x[n0-254 .. n0+8065] as bf16 hi/lo, XOR-swizzled at 16B-chunk level
  for (int e = tid; e < STG; e += BLOCK) {
    const int gi = n0 - 254 + e;
    const float v = (gi >= 0) ? xrow[gi] : 0.f;
    const unsigned short hi = f2bf(v);
    const unsigned short lo = f2bf(v - bf2f(hi));
    const int ch  = e >> 3;
    const int pos = ((ch ^ ((ch >> 3) & 7)) << 3) | (e & 7);
    xh[pos] = hi;
    xl[pos] = lo;
  }
  __syncthreads();

  const int p = lane & 31, g = lane >> 5;
  f32x16 acc[TPW] = {};

  const int eb = wid * 2048 + 8 * g + 32 * p;
  #pragma unroll
  for (int c = 0; c < NCH; ++c) {
    #pragma unroll
    for (int tt = 0; tt < TPW; ++tt) {
      const int e0  = eb + tt * 1024 + 16 * c;          // chunk-aligned (mult of 8)
      const int ch  = e0 >> 3;
      const int off = (ch ^ ((ch >> 3) & 7)) << 3;
      const short8 bh = *(const short8*)(xh + off);
      const short8 bl = *(const short8*)(xl + off);
      acc[tt] = __builtin_amdgcn_mfma_f32_32x32x16_bf16(AHf[c], bh, acc[tt], 0, 0, 0);
      acc[tt] = __builtin_amdgcn_mfma_f32_32x32x16_bf16(ALf[c], bh, acc[tt], 0, 0, 0);
      acc[tt] = __builtin_amdgcn_mfma_f32_32x32x16_bf16(AHf[c], bl, acc[tt], 0, 0, 0);
    }
  }
  __syncthreads();                                       // done reading staged x

  // epilogue: transpose D tiles through LDS (pad 32->33), then coalesced stores
  float* ebuf = (float*)smem;
  #pragma unroll
  for (int tt = 0; tt < TPW; ++tt) {
    const int tb = (wid * TPW + tt) * 1056;
    #pragma unroll
    for (int r = 0; r < 16; ++r) {
      const int m = (r & 3) + 8 * (r >> 2) + 4 * g;      // verified C/D row map
      ebuf[tb + p * 33 + m] = acc[tt][r];                // col = p = lane&31
    }
  }
  __syncthreads();

  float* __restrict__ orow = out + (size_t)row * T_LEN + n0;
  #pragma unroll
  for (int i = 0; i < 8; ++i) {
    const int o  = 4 * tid + 1024 * i;
    const int tt = o >> 10, oo = o & 1023;
    const int m0 = oo & 31, nn = oo >> 5;
    const int b  = tt * 1056 + nn * 33 + m0;
    float4 v;
    v.x = ebuf[b]; v.y = ebuf[b + 1]; v.z = ebuf[b + 2]; v.w = ebuf[b + 3];
    *(float4*)(orow + o) = v;
  }
}

// ---- kernel 3: wraparound fixup for n in [0,126] (fp32 exact) ----
__global__ __launch_bounds__(NTAPS) void ssm_fix(
    const float* __restrict__ x, const float* __restrict__ ws,
    float* __restrict__ out) {
  const int row = blockIdx.x;
  const int n = threadIdx.x;
  if (n >= NTAPS - 1) return;
  const float* __restrict__ h = ws;          // plain h at ws[0..127]
  const float* __restrict__ xrow = x + (size_t)row * T_LEN;
  float acc = 0.f;
  for (int k = n + 1; k < NTAPS; ++k)
    acc += h[k] * xrow[T_LEN + n - k];
  out[(size_t)row * T_LEN + n] = acc;
}

extern "C" void kernel_launch(void* const* d_in, const int* in_sizes, int n_in,
                              void* d_out, int out_size, void* d_ws, size_t ws_size,
                              hipStream_t stream) {
  const float* x      = (const float*)d_in[0];
  const float* w_real = (const float*)d_in[1];
  const float* w_imag = (const float*)d_in[2];
  const float* log_dt = (const float*)d_in[3];
  const float* C_real = (const float*)d_in[4];
  const float* C_imag = (const float*)d_in[5];
  const float* B_real = (const float*)d_in[6];
  const float* B_imag = (const float*)d_in[7];
  const float* Dp     = (const float*)d_in[8];
  float* out = (float*)d_out;
  float* ws  = (float*)d_ws;   // 128 f32 h + 2*NCH*64*8 ushort A-frags = 20.9 KB

  ssm_taps<<<1, NTAPS, 0, stream>>>(w_real, w_imag, log_dt,
                                    C_real, C_imag, B_real, B_imag, Dp, ws);
  dim3 grid(T_LEN / NOUT, NROWS);
  ssm_conv<<<grid, BLOCK, 0, stream>>>(x, ws, out);
  ssm_fix<<<NROWS, NTAPS, 0, stream>>>(x, ws, out);
}